// Round 4
// baseline (340.150 us; speedup 1.0000x reference)
//
#include <hip/hip_runtime.h>
#include <math.h>

// Problem constants (fixed by the reference harness)
#define BATCH 4
#define SEQ   4096
#define DIM   1024
#define TOPK  64          // min(GLOBAL_BUDGET=64, int(4096*0.05)=204)
#define RSTRIDE 10        // max(1, 4096 // 409)
#define RBUDGET 409       // min(4096, int(4096*0.1))
#define LOCALW  128

typedef float nfloat4 __attribute__((ext_vector_type(4)));

// d_ws layout:
//   [0, BATCH*SEQ) floats : scores
//   then BATCH*SEQ bytes  : flags (bit0=valid, bit1=global, bit2=random)
#define WS_SCORES_OFF 0
#define WS_FLAGS_OFF  (BATCH * SEQ * sizeof(float))

// One wave (64 lanes) per (b,s) row: score = dot(hidden[b,s,:], W)
__global__ void scores_kernel(const float* __restrict__ hs,
                              const int* __restrict__ amask,
                              const float* __restrict__ W,
                              float* __restrict__ scores) {
    int row  = blockIdx.x * 4 + (threadIdx.x >> 6);   // 4 waves / block
    int lane = threadIdx.x & 63;
    const float4* h4 = (const float4*)(hs + (size_t)row * DIM);
    const float4* w4 = (const float4*)W;
    float acc = 0.0f;
#pragma unroll
    for (int k = 0; k < DIM / 4 / 64; ++k) {          // 4 iterations
        float4 h = h4[lane + 64 * k];
        float4 w = w4[lane + 64 * k];
        acc += h.x * w.x + h.y * w.y + h.z * w.z + h.w * w.w;
    }
#pragma unroll
    for (int off = 32; off; off >>= 1) acc += __shfl_down(acc, off, 64);
    if (lane == 0)
        scores[row] = amask[row] ? acc : -INFINITY;
}

// One block per batch. Fuses: exact top-64 (4-pass byte radix select, ties ->
// lowest index like jax.lax.top_k), flag-byte emission, analytic connection
// count via column prefix sums, selected=1.0 write, efficiency write.
__global__ void topk_fused_kernel(const float* __restrict__ scores,
                                  const int* __restrict__ amask,
                                  unsigned char* __restrict__ flags,
                                  float* __restrict__ out_selected,
                                  float* __restrict__ out_eff) {
    __shared__ unsigned int su[SEQ];          // keys; reused as cumV later
    __shared__ int cumH[SEQ];
    __shared__ unsigned char gsel[SEQ];
    __shared__ unsigned char sflags[SEQ];
    __shared__ unsigned int hist[257];
    __shared__ unsigned int sufA[257];
    __shared__ unsigned int sufB[257];
    __shared__ unsigned int bcast[2];
    __shared__ int tvA[256], tvB[256], thA[256], thB[256], red[256];

    int b = blockIdx.x, t = threadIdx.x;

    // ---- load + monotonic float->uint map ----
    for (int k = t; k < SEQ; k += 256) {
        float s = scores[b * SEQ + k];
        unsigned int x = __float_as_uint(s);
        su[k] = (x & 0x80000000u) ? ~x : (x | 0x80000000u);
        gsel[k] = 0;
    }
    __syncthreads();

    // ---- 4-pass radix select for threshold T and tie count ----
    unsigned int prefixVal = 0;
    unsigned int remaining = TOPK;
#pragma unroll
    for (int pass = 0; pass < 4; ++pass) {
        int shift = 24 - 8 * pass;
        unsigned int highmask = (pass == 0) ? 0u : (0xFFFFFFFFu << (shift + 8));

        hist[t] = 0;
        if (t == 0) hist[256] = 0;
        __syncthreads();
#pragma unroll
        for (int e = 0; e < SEQ / 256; ++e) {
            unsigned int u = su[t * (SEQ / 256) + e];
            if ((u & highmask) == prefixVal)
                atomicAdd(&hist[(u >> shift) & 0xFFu], 1u);
        }
        __syncthreads();

        sufA[t] = hist[t];
        if (t == 0) sufA[256] = 0;
        __syncthreads();
        unsigned int* src = sufA;
        unsigned int* dst = sufB;
        for (int d = 1; d < 256; d <<= 1) {
            unsigned int v = src[t] + ((t + d < 256) ? src[t + d] : 0u);
            dst[t] = v;
            if (t == 0) dst[256] = 0;
            __syncthreads();
            unsigned int* tmp = src; src = dst; dst = tmp;
        }
        if (src[t] >= remaining && src[t + 1] < remaining) {
            bcast[0] = (unsigned int)t;
            bcast[1] = remaining - src[t + 1];
        }
        __syncthreads();
        prefixVal |= (bcast[0] << shift);
        remaining = bcast[1];
        __syncthreads();
    }

    // ---- stable tie fill: `remaining` lowest-index elements == T ----
    unsigned int T = prefixVal;
    unsigned int myeq = 0;
#pragma unroll
    for (int e = 0; e < SEQ / 256; ++e)
        if (su[t * (SEQ / 256) + e] == T) myeq++;
    sufA[t] = myeq;
    __syncthreads();
    {
        unsigned int* src = sufA;
        unsigned int* dst = sufB;
        for (int d = 1; d < 256; d <<= 1) {
            unsigned int v = src[t] + ((t >= d) ? src[t - d] : 0u);
            dst[t] = v;
            __syncthreads();
            unsigned int* tmp = src; src = dst; dst = tmp;
        }
        unsigned int taken = src[t] - myeq;
#pragma unroll
        for (int e = 0; e < SEQ / 256; ++e) {
            int idx = t * (SEQ / 256) + e;
            unsigned int u = su[idx];
            if (u > T) gsel[idx] = 1;
            else if (u == T) { if (taken < remaining) gsel[idx] = 1; taken++; }
        }
    }
    __syncthreads();

    // ---- flags (global + LDS) and selected ----
    for (int k = t; k < SEQ; k += 256) {
        int valid = (amask[b * SEQ + k] != 0) ? 1 : 0;
        int g = gsel[k];
        int r = ((k % RSTRIDE) == 0 && (k / RSTRIDE) < RBUDGET) ? 1 : 0;
        unsigned char f = (unsigned char)(valid | (g << 1) | (r << 2));
        flags[b * SEQ + k] = f;
        sflags[k] = f;
        out_selected[b * SEQ + k] = 1.0f;   // local.any(axis=0) is all-True
    }
    __syncthreads();

    // ---- analytic count: one(i,j)=(j<=i)&vI&vJ&(i-j<128 | hotI | hotJ) ----
    int* cumV = (int*)su;                   // su is dead; reuse its LDS
    int lv[16], lh[16];
    int sv = 0, sh = 0;
#pragma unroll
    for (int e = 0; e < 16; ++e) {
        unsigned char f = sflags[t * 16 + e];
        int v = f & 1;
        int h = v & (((f & 6) != 0) ? 1 : 0);
        sv += v; sh += h;
        lv[e] = sv; lh[e] = sh;
    }
    tvA[t] = sv; thA[t] = sh;
    __syncthreads();
    int* vsrc = tvA; int* vdst = tvB;
    int* hsrc = thA; int* hdst = thB;
    for (int d = 1; d < 256; d <<= 1) {
        int av = vsrc[t] + ((t >= d) ? vsrc[t - d] : 0);
        int ah = hsrc[t] + ((t >= d) ? hsrc[t - d] : 0);
        vdst[t] = av; hdst[t] = ah;
        __syncthreads();
        int* tmp = vsrc; vsrc = vdst; vdst = tmp;
        tmp = hsrc; hsrc = hdst; hdst = tmp;
    }
    int bv = vsrc[t] - sv, bh = hsrc[t] - sh;
#pragma unroll
    for (int e = 0; e < 16; ++e) {
        cumV[t * 16 + e] = lv[e] + bv;
        cumH[t * 16 + e] = lh[e] + bh;
    }
    __syncthreads();

    int cnt = 0;
#pragma unroll
    for (int e = 0; e < 16; ++e) {
        int i = t * 16 + e;
        unsigned char f = sflags[i];
        int validI = f & 1;
        int hotI = (f & 6) != 0;
        int c;
        if (hotI) c = cumV[i];
        else {
            int w = (i >= LOCALW) ? (cumV[i] - cumV[i - LOCALW]) : cumV[i];
            int g = (i >= LOCALW) ? cumH[i - LOCALW] : 0;
            c = w + g;
        }
        cnt += validI ? c : 0;
    }
    red[t] = cnt;
    __syncthreads();
    for (int s2 = 128; s2; s2 >>= 1) {
        if (t < s2) red[t] += red[t + s2];
        __syncthreads();
    }
    if (t == 0)
        out_eff[b] = (float)red[0] * (1.0f / ((float)SEQ * (float)SEQ));
}

// 8 rows per block, plain (L2-aggregated) float4 stores, no LDS/barrier/atomic.
// Per-thread precomputed row patterns A=[vJ], C=[vJ&hotJ]; each row is a
// 3-segment select (zero / window / prefix); per-element work only at the
// <=2 boundary groups per row.
__global__ void __launch_bounds__(256) mask_kernel(
        const unsigned char* __restrict__ flags,
        float* __restrict__ out) {
    int row0 = blockIdx.x << 3;          // 8 consecutive rows, same batch
    int b = row0 >> 12;
    int t = threadIdx.x;

    const uchar4* f4 = (const uchar4*)(flags + b * SEQ);
    nfloat4 A[4], C[4];
#pragma unroll
    for (int k = 0; k < 4; ++k) {
        uchar4 f = f4[t + 256 * k];
        unsigned char fa[4] = {f.x, f.y, f.z, f.w};
#pragma unroll
        for (int e = 0; e < 4; ++e) {
            int v = fa[e] & 1;
            int h = (fa[e] & 6) != 0;
            A[k][e] = v ? 1.0f : 0.0f;
            C[k][e] = (v & h) ? 1.0f : 0.0f;
        }
    }

    // 8 row-flag bytes (row0 % 8 == 0, flags index b*SEQ+i == row0+r)
    uchar4 frA = *(const uchar4*)(flags + row0);
    uchar4 frB = *(const uchar4*)(flags + row0 + 4);
    unsigned char fra[8] = {frA.x, frA.y, frA.z, frA.w, frB.x, frB.y, frB.z, frB.w};

    const nfloat4 zero4 = {0.0f, 0.0f, 0.0f, 0.0f};

#pragma unroll
    for (int r = 0; r < 8; ++r) {
        int i = (row0 + r) & (SEQ - 1);
        int validI = fra[r] & 1;
        int hotI = (fra[r] & 6) != 0;
        nfloat4* outrow4 = (nfloat4*)(out + (size_t)(row0 + r) * SEQ);
#pragma unroll
        for (int k = 0; k < 4; ++k) {
            int j4 = t + 256 * k;
            int j0 = j4 << 2;
            nfloat4 outv;
            if (!validI || j0 > i) {
                outv = zero4;                               // all-zero segment
            } else if (j0 + 3 <= i && j0 + (LOCALW - 1) >= i) {
                outv = A[k];                                // fully in window
            } else if (j0 + 3 <= i - LOCALW) {
                outv = hotI ? A[k] : C[k];                  // fully in prefix
            } else {                                        // boundary group
#pragma unroll
                for (int e = 0; e < 4; ++e) {
                    int j = j0 + e;
                    float av = A[k][e];
                    float base = (j + (LOCALW - 1) >= i) ? av
                               : (hotI ? av : C[k][e]);
                    outv[e] = (j <= i) ? base : 0.0f;
                }
            }
            outrow4[j4] = outv;
        }
    }
}

extern "C" void kernel_launch(void* const* d_in, const int* in_sizes, int n_in,
                              void* d_out, int out_size, void* d_ws, size_t ws_size,
                              hipStream_t stream) {
    const float* hs    = (const float*)d_in[0];   // [B,S,D] f32
    const int*   amask = (const int*)d_in[1];     // [B,S] i32
    const float* W     = (const float*)d_in[2];   // [1,D] f32

    char* ws = (char*)d_ws;
    float*         scores = (float*)(ws + WS_SCORES_OFF);
    unsigned char* flags  = (unsigned char*)(ws + WS_FLAGS_OFF);

    float* out_sparse   = (float*)d_out;                          // B*S*S
    float* out_selected = out_sparse + (size_t)BATCH * SEQ * SEQ; // B*S
    float* out_eff      = out_selected + BATCH * SEQ;             // B

    scores_kernel<<<BATCH * SEQ / 4, 256, 0, stream>>>(hs, amask, W, scores);
    topk_fused_kernel<<<BATCH, 256, 0, stream>>>(scores, amask, flags,
                                                 out_selected, out_eff);
    mask_kernel<<<BATCH * SEQ / 8, 256, 0, stream>>>(flags, out_sparse);
}

// Round 5
// 337.745 us; speedup vs baseline: 1.0071x; 1.0071x over previous
//
#include <hip/hip_runtime.h>
#include <math.h>

// Problem constants (fixed by the reference harness)
#define BATCH 4
#define SEQ   4096
#define DIM   1024
#define TOPK  64          // min(GLOBAL_BUDGET=64, int(4096*0.05)=204)
#define RSTRIDE 10        // max(1, 4096 // 409)
#define RBUDGET 409       // min(4096, int(4096*0.1))
#define LOCALW  128

typedef float nfloat4 __attribute__((ext_vector_type(4)));

// d_ws layout:
//   [0, BATCH*SEQ) floats : scores
//   then BATCH*SEQ bytes  : flags (bit0=valid, bit1=global, bit2=random)
#define WS_SCORES_OFF 0
#define WS_FLAGS_OFF  (BATCH * SEQ * sizeof(float))

// One wave (64 lanes) per (b,s) row: score = dot(hidden[b,s,:], W)
__global__ void scores_kernel(const float* __restrict__ hs,
                              const int* __restrict__ amask,
                              const float* __restrict__ W,
                              float* __restrict__ scores) {
    int row  = blockIdx.x * 4 + (threadIdx.x >> 6);   // 4 waves / block
    int lane = threadIdx.x & 63;
    const float4* h4 = (const float4*)(hs + (size_t)row * DIM);
    const float4* w4 = (const float4*)W;
    float acc = 0.0f;
#pragma unroll
    for (int k = 0; k < DIM / 4 / 64; ++k) {          // 4 iterations
        float4 h = h4[lane + 64 * k];
        float4 w = w4[lane + 64 * k];
        acc += h.x * w.x + h.y * w.y + h.z * w.z + h.w * w.w;
    }
#pragma unroll
    for (int off = 32; off; off >>= 1) acc += __shfl_down(acc, off, 64);
    if (lane == 0)
        scores[row] = amask[row] ? acc : -INFINITY;
}

// One block per batch. Fuses: exact top-64 (4-pass byte radix select, ties ->
// lowest index like jax.lax.top_k), flag-byte emission, analytic connection
// count via column prefix sums, selected=1.0 write, efficiency write.
__global__ void topk_fused_kernel(const float* __restrict__ scores,
                                  const int* __restrict__ amask,
                                  unsigned char* __restrict__ flags,
                                  float* __restrict__ out_selected,
                                  float* __restrict__ out_eff) {
    __shared__ unsigned int su[SEQ];          // keys; reused as cumV later
    __shared__ int cumH[SEQ];
    __shared__ unsigned char gsel[SEQ];
    __shared__ unsigned char sflags[SEQ];
    __shared__ unsigned int hist[257];
    __shared__ unsigned int sufA[257];
    __shared__ unsigned int sufB[257];
    __shared__ unsigned int bcast[2];
    __shared__ int tvA[256], tvB[256], thA[256], thB[256], red[256];

    int b = blockIdx.x, t = threadIdx.x;

    // ---- load + monotonic float->uint map ----
    for (int k = t; k < SEQ; k += 256) {
        float s = scores[b * SEQ + k];
        unsigned int x = __float_as_uint(s);
        su[k] = (x & 0x80000000u) ? ~x : (x | 0x80000000u);
        gsel[k] = 0;
    }
    __syncthreads();

    // ---- 4-pass radix select for threshold T and tie count ----
    unsigned int prefixVal = 0;
    unsigned int remaining = TOPK;
#pragma unroll
    for (int pass = 0; pass < 4; ++pass) {
        int shift = 24 - 8 * pass;
        unsigned int highmask = (pass == 0) ? 0u : (0xFFFFFFFFu << (shift + 8));

        hist[t] = 0;
        if (t == 0) hist[256] = 0;
        __syncthreads();
#pragma unroll
        for (int e = 0; e < SEQ / 256; ++e) {
            unsigned int u = su[t * (SEQ / 256) + e];
            if ((u & highmask) == prefixVal)
                atomicAdd(&hist[(u >> shift) & 0xFFu], 1u);
        }
        __syncthreads();

        sufA[t] = hist[t];
        if (t == 0) sufA[256] = 0;
        __syncthreads();
        unsigned int* src = sufA;
        unsigned int* dst = sufB;
        for (int d = 1; d < 256; d <<= 1) {
            unsigned int v = src[t] + ((t + d < 256) ? src[t + d] : 0u);
            dst[t] = v;
            if (t == 0) dst[256] = 0;
            __syncthreads();
            unsigned int* tmp = src; src = dst; dst = tmp;
        }
        if (src[t] >= remaining && src[t + 1] < remaining) {
            bcast[0] = (unsigned int)t;
            bcast[1] = remaining - src[t + 1];
        }
        __syncthreads();
        prefixVal |= (bcast[0] << shift);
        remaining = bcast[1];
        __syncthreads();
    }

    // ---- stable tie fill: `remaining` lowest-index elements == T ----
    unsigned int T = prefixVal;
    unsigned int myeq = 0;
#pragma unroll
    for (int e = 0; e < SEQ / 256; ++e)
        if (su[t * (SEQ / 256) + e] == T) myeq++;
    sufA[t] = myeq;
    __syncthreads();
    {
        unsigned int* src = sufA;
        unsigned int* dst = sufB;
        for (int d = 1; d < 256; d <<= 1) {
            unsigned int v = src[t] + ((t >= d) ? src[t - d] : 0u);
            dst[t] = v;
            __syncthreads();
            unsigned int* tmp = src; src = dst; dst = tmp;
        }
        unsigned int taken = src[t] - myeq;
#pragma unroll
        for (int e = 0; e < SEQ / 256; ++e) {
            int idx = t * (SEQ / 256) + e;
            unsigned int u = su[idx];
            if (u > T) gsel[idx] = 1;
            else if (u == T) { if (taken < remaining) gsel[idx] = 1; taken++; }
        }
    }
    __syncthreads();

    // ---- flags (global + LDS) and selected ----
    for (int k = t; k < SEQ; k += 256) {
        int valid = (amask[b * SEQ + k] != 0) ? 1 : 0;
        int g = gsel[k];
        int r = ((k % RSTRIDE) == 0 && (k / RSTRIDE) < RBUDGET) ? 1 : 0;
        unsigned char f = (unsigned char)(valid | (g << 1) | (r << 2));
        flags[b * SEQ + k] = f;
        sflags[k] = f;
        out_selected[b * SEQ + k] = 1.0f;   // local.any(axis=0) is all-True
    }
    __syncthreads();

    // ---- analytic count: one(i,j)=(j<=i)&vI&vJ&(i-j<128 | hotI | hotJ) ----
    int* cumV = (int*)su;                   // su is dead; reuse its LDS
    int lv[16], lh[16];
    int sv = 0, sh = 0;
#pragma unroll
    for (int e = 0; e < 16; ++e) {
        unsigned char f = sflags[t * 16 + e];
        int v = f & 1;
        int h = v & (((f & 6) != 0) ? 1 : 0);
        sv += v; sh += h;
        lv[e] = sv; lh[e] = sh;
    }
    tvA[t] = sv; thA[t] = sh;
    __syncthreads();
    int* vsrc = tvA; int* vdst = tvB;
    int* hsrc = thA; int* hdst = thB;
    for (int d = 1; d < 256; d <<= 1) {
        int av = vsrc[t] + ((t >= d) ? vsrc[t - d] : 0);
        int ah = hsrc[t] + ((t >= d) ? hsrc[t - d] : 0);
        vdst[t] = av; hdst[t] = ah;
        __syncthreads();
        int* tmp = vsrc; vsrc = vdst; vdst = tmp;
        tmp = hsrc; hsrc = hdst; hdst = tmp;
    }
    int bv = vsrc[t] - sv, bh = hsrc[t] - sh;
#pragma unroll
    for (int e = 0; e < 16; ++e) {
        cumV[t * 16 + e] = lv[e] + bv;
        cumH[t * 16 + e] = lh[e] + bh;
    }
    __syncthreads();

    int cnt = 0;
#pragma unroll
    for (int e = 0; e < 16; ++e) {
        int i = t * 16 + e;
        unsigned char f = sflags[i];
        int validI = f & 1;
        int hotI = (f & 6) != 0;
        int c;
        if (hotI) c = cumV[i];
        else {
            int w = (i >= LOCALW) ? (cumV[i] - cumV[i - LOCALW]) : cumV[i];
            int g = (i >= LOCALW) ? cumH[i - LOCALW] : 0;
            c = w + g;
        }
        cnt += validI ? c : 0;
    }
    red[t] = cnt;
    __syncthreads();
    for (int s2 = 128; s2; s2 >>= 1) {
        if (t < s2) red[t] += red[t + s2];
        __syncthreads();
    }
    if (t == 0)
        out_eff[b] = (float)red[0] * (1.0f / ((float)SEQ * (float)SEQ));
}

// Fill-isomorphic mask writer: flat grid-stride over all B*S*S/4 float4
// groups. Per iteration: 1 broadcast byte load (row flag), 1 coalesced
// uchar4 load (col flags, 16 KB table -> L1-resident), ~branchless compute,
// 1 float4 store. Low VGPR, no LDS, no barriers, no unrolled register blocks.
#define MASK_BLOCKS 8192
__global__ void __launch_bounds__(256) mask_kernel(
        const unsigned char* __restrict__ flags,
        float* __restrict__ out) {
    const uchar4* f4all = (const uchar4*)flags;
    nfloat4* out4 = (nfloat4*)out;
    int p = blockIdx.x * 256 + threadIdx.x;       // float4 index
    const int stride = MASK_BLOCKS * 256;
#pragma unroll
    for (int it = 0; it < (BATCH * SEQ * SEQ / 4) / (MASK_BLOCKS * 256); ++it) {
        int row = p >> 10;                        // 1024 float4 per row; row = b*SEQ+i
        int i = row & (SEQ - 1);
        int bbase = (row >> 12) << 10;            // b * (SEQ/4) uchar4
        unsigned char fi = flags[row];            // wave-uniform broadcast
        int validI = fi & 1;
        int hotI = (fi & 6) != 0;
        int jg = p & 1023;
        uchar4 fj = f4all[bbase + jg];
        unsigned char fja[4] = {fj.x, fj.y, fj.z, fj.w};
        int j0 = jg << 2;
        nfloat4 v;
#pragma unroll
        for (int e = 0; e < 4; ++e) {
            int j = j0 + e;
            unsigned char f = fja[e];
            int one = (j <= i) & validI & (int)(f & 1)
                    & (((i - j) < LOCALW) | hotI | (int)((f & 6) != 0));
            v[e] = one ? 1.0f : 0.0f;
        }
        out4[p] = v;
        p += stride;
    }
}

extern "C" void kernel_launch(void* const* d_in, const int* in_sizes, int n_in,
                              void* d_out, int out_size, void* d_ws, size_t ws_size,
                              hipStream_t stream) {
    const float* hs    = (const float*)d_in[0];   // [B,S,D] f32
    const int*   amask = (const int*)d_in[1];     // [B,S] i32
    const float* W     = (const float*)d_in[2];   // [1,D] f32

    char* ws = (char*)d_ws;
    float*         scores = (float*)(ws + WS_SCORES_OFF);
    unsigned char* flags  = (unsigned char*)(ws + WS_FLAGS_OFF);

    float* out_sparse   = (float*)d_out;                          // B*S*S
    float* out_selected = out_sparse + (size_t)BATCH * SEQ * SEQ; // B*S
    float* out_eff      = out_selected + BATCH * SEQ;             // B

    scores_kernel<<<BATCH * SEQ / 4, 256, 0, stream>>>(hs, amask, W, scores);
    topk_fused_kernel<<<BATCH, 256, 0, stream>>>(scores, amask, flags,
                                                 out_selected, out_eff);
    mask_kernel<<<MASK_BLOCKS, 256, 0, stream>>>(flags, out_sparse);
}